// Round 12
// baseline (216.767 us; speedup 1.0000x reference)
//
#include <hip/hip_runtime.h>
#include <hip/hip_bf16.h>

#define TDIM 256
#define VDIM 25
#define CDIM 64
#define BDIM 32
#define EPSV 1e-5f

// ws layout
#define XM_OFF     0            // 51200 floats
#define LOSSP_OFF  51200        // 3072 floats (1024 blocks * 3)
#define WPACK_BYTE 229376       // 96 packs * 9216 shorts (bf16 z B-frags, 32x32x16)
#define WL_SH      9216         // shorts per (b,s): 18 kk * (2 hf * 32 n * 8 j)
#define W3P_BYTE   (WPACK_BYTE + 96 * WL_SH * 2)  // 3s*4096 shorts (y A-frags, 16x16x16)

typedef short s4v __attribute__((ext_vector_type(4)));
typedef short s8v __attribute__((ext_vector_type(8)));
typedef float f4v __attribute__((ext_vector_type(4)));
typedef float f16v __attribute__((ext_vector_type(16)));

__device__ __forceinline__ unsigned f2bf(float f) {
  __hip_bfloat16 h = __float2bfloat16(f);
  return (unsigned)__builtin_bit_cast(unsigned short, h);
}
__device__ __forceinline__ float bf2f(unsigned short u) {
  unsigned v = ((unsigned)u) << 16;
  return __builtin_bit_cast(float, v);
}

// raw barrier, no waitcnt drain (BZ): sync wave arrival only
#define BARRIER_RAW() do {                        \
  asm volatile("" ::: "memory");                  \
  __builtin_amdgcn_sched_barrier(0);              \
  __builtin_amdgcn_s_barrier();                   \
  __builtin_amdgcn_sched_barrier(0);              \
  asm volatile("" ::: "memory");                  \
} while (0)

// barrier with LDS-only drain (BB): ds writes visible, vmem (DMA) stays in flight
#define BARRIER_LDS() do {                        \
  __builtin_amdgcn_sched_barrier(0);              \
  asm volatile("s_waitcnt lgkmcnt(0)" ::: "memory"); \
  __builtin_amdgcn_s_barrier();                   \
  __builtin_amdgcn_sched_barrier(0);              \
  asm volatile("" ::: "memory");                  \
} while (0)

// ---------------- Kernel 1: xm[b,c,v] = mean over T ----------------
__global__ __launch_bounds__(256) void kmean(const float* __restrict__ x,
                                             float* __restrict__ ws) {
  int bc = blockIdx.x;
  int tid = threadIdx.x;
  int vl = tid & 31, tr = tid >> 5;
  float acc = 0.f;
  if (vl < VDIM) {
    const float* p = x + (size_t)bc * TDIM * VDIM + vl;
    for (int t = tr; t < TDIM; t += 8) acc += p[(size_t)t * VDIM];
  }
  __shared__ float red[256];
  red[tid] = acc;
  __syncthreads();
  if (tr == 0 && vl < VDIM) {
    float s = 0.f;
    for (int r = 0; r < 8; ++r) s += red[r * 32 + vl];
    ws[XM_OFF + bc * VDIM + vl] = s * (1.f / 256.f);
  }
}

// ---------------- Kernel 2: dynamic weights -> packed bf16 fragments ----------------
__global__ __launch_bounds__(256) void kadj(const float* __restrict__ A,
                                            const float* __restrict__ alpha,
                                            const float* __restrict__ W1,
                                            const float* __restrict__ b1,
                                            const float* __restrict__ W2,
                                            const float* __restrict__ b2,
                                            const float* __restrict__ W3,
                                            float* __restrict__ ws,
                                            float* __restrict__ out_ridge) {
  int s = blockIdx.x >> 5, b = blockIdx.x & 31;
  int tid = threadIdx.x;
  __shared__ float xm[CDIM * VDIM];
  __shared__ float w1l[9 * CDIM], w2l[9 * CDIM];
  __shared__ float b1l[9], b2l[9];
  __shared__ float x1l[9 * VDIM], x2l[9 * VDIM];
  __shared__ float red[256];
  __shared__ float wsm[9 * VDIM * VDIM];   // w[k][v][i] f32

  for (int i = tid; i < CDIM * VDIM; i += 256) xm[i] = ws[XM_OFF + b * CDIM * VDIM + i];
  for (int i = tid; i < 9 * CDIM; i += 256) {
    w1l[i] = W1[s * 9 * CDIM + i];
    w2l[i] = W2[s * 9 * CDIM + i];
  }
  if (tid < 9) { b1l[tid] = b1[s * 9 + tid]; b2l[tid] = b2[s * 9 + tid]; }
  __syncthreads();

  if (tid < 9 * VDIM) {
    int ts = tid / VDIM, v = tid % VDIM;
    float a1 = 0.f, a2 = 0.f;
    for (int c = 0; c < CDIM; ++c) {
      float xv = xm[c * VDIM + v];
      a1 = fmaf(xv, w1l[ts * CDIM + c], a1);
      a2 = fmaf(xv, w2l[ts * CDIM + c], a2);
    }
    x1l[tid] = a1 + b1l[ts];
    x2l[tid] = a2 + b2l[ts];
  }
  __syncthreads();

  float al = alpha[0];
  float rid = 0.f;
  for (int idx = tid; idx < 9 * VDIM * VDIM; idx += 256) {
    int k = idx / (VDIM * VDIM);
    int r = (idx / VDIM) % VDIM;   // v
    int q = idx % VDIM;            // i
    float adj = tanhf(x1l[k * VDIM + r] - x2l[k * VDIM + q]);
    rid += adj * adj;
    wsm[idx] = fmaf(adj, al, A[(s * VDIM + r) * VDIM + q]);
  }
  red[tid] = rid;
  __syncthreads();   // wsm + red complete

  // pack z B-frags for 32x32x16: [kk 18][hf 2][n 32][j 8]
  // lane l reads its 8 shorts at wl + l*8:  l*8+j == hf*256 + n*8 + j  (hf=l>>5, n=l&31)
  {
    unsigned short* wp = (unsigned short*)((char*)ws + WPACK_BYTE) + (size_t)(b * 3 + s) * WL_SH;
    for (int idx = tid; idx < WL_SH; idx += 256) {
      int kk = idx >> 9;           // 0..17
      int rem = idx & 511;
      int hf = rem >> 8;           // 0..1
      int n = (rem >> 3) & 31;     // i
      int j = rem & 7;
      int k = kk >> 1, vh = kk & 1;
      int v = vh * 16 + hf * 8 + j;
      float val = (v < VDIM && n < VDIM) ? wsm[(k * VDIM + v) * VDIM + n] : 0.f;
      wp[idx] = (unsigned short)f2bf(val);
    }
  }

  for (int st = 128; st > 0; st >>= 1) {
    if (tid < st) red[tid] += red[tid + st];
    __syncthreads();
  }
  if (tid == 0) out_ridge[s * BDIM + b] = red[0];

  // pack W3 A-frags (16x16x16): [s][p][mt][col16][g4][j4]
  if (b == 0) {
    unsigned short* w3p = (unsigned short*)((char*)ws + W3P_BYTE) + s * 4096;
    for (int idx = tid; idx < 4096; idx += 256) {
      int pm = idx >> 8;          // p*4+mt
      int p = pm >> 2, mt = pm & 3;
      int e = idx & 255;
      int colv = e >> 4, gg = (e >> 2) & 3, jj = e & 3;
      int o = mt * 16 + colv, c = p * 16 + gg * 4 + jj;
      w3p[idx] = (unsigned short)f2bf(W3[(s * CDIM + o) * CDIM + c]);
    }
  }
}

// ---------------- Kernel 3: fused z(32x32 MFMA) -> (loss, y(16x16)), t-tile = 8 ----------------
// Phase: z (2 indep acc chains) | BZ | DMA next wl | loss->zly | BB | y | syncthreads
// Epilogue: yacc -> LDS stage -> coalesced BN+residual+relu writes
__global__ __launch_bounds__(256, 3) void kmain(const float* __restrict__ x,
                                                const float* __restrict__ b3,
                                                const float* __restrict__ bng,
                                                const float* __restrict__ bnb,
                                                const float* __restrict__ bnm,
                                                const float* __restrict__ bnv,
                                                const float* __restrict__ ws,
                                                float* __restrict__ out,
                                                float* __restrict__ lossP) {
  const int id   = blockIdx.x;                      // 0..31
  const int tile = ((id & 7) << 2) | (id >> 3);     // XCD-contiguous t-chunks
  const int b    = blockIdx.y;
  const int t0   = tile * 8;
  const int tid  = threadIdx.x;
  const int wid  = tid >> 6;
  const int lane = tid & 63;
  const int w4   = wid * 4;
  // z lane constants (32x32)
  const int col32 = lane & 31;
  const int half  = lane >> 5;
  const int t_l   = lane & 7;
  const int c_sl  = w4 + ((lane & 31) >> 3);
  // y lane constants (16x16)
  const int col16 = lane & 15;
  const int g     = (lane >> 4) & 3;

  __shared__ __align__(16) short wl[WL_SH];       // 18432 B
  __shared__ __align__(16) unsigned xw_u[4096];   // 16384 B (reused as f32 stage)
  __shared__ __align__(16) short zly[4608];       // 9216 B
  __shared__ float bnf[128];

  if (tid < 64) {
    float inv = bng[tid] / sqrtf(bnv[tid] + EPSV);
    bnf[tid] = inv;
    bnf[64 + tid] = (b3[tid] + b3[64 + tid] + b3[128 + tid] - bnm[tid]) * inv + bnb[tid];
  }

  const unsigned short* wpack = (const unsigned short*)((const char*)ws + WPACK_BYTE);
  const unsigned short* w3p   = (const unsigned short*)((const char*)ws + W3P_BYTE);

  auto stage_wl = [&](int s2) {
    const char* src = (const char*)(wpack + (size_t)(b * 3 + s2) * WL_SH);
#pragma unroll
    for (int j = 0; j < 5; ++j) {
      int off = j * 4096 + wid * 1024;
      if (off < WL_SH * 2) {
        __builtin_amdgcn_global_load_lds(
            (const __attribute__((address_space(1))) unsigned*)(src + off + lane * 16),
            (__attribute__((address_space(3))) unsigned*)((char*)wl + off + lane * 16),
            16, 0, 0);
      }
    }
  };

  auto stage_xw = [&](int p) {
    int c_s = tid >> 4, r = tid & 15;       // row tp = r
    int gt = t0 - 8 + r;
    int key = (r + c_s) & 3;
    unsigned hv[16];
    if (gt >= 0) {
      const float* rp = x + ((size_t)(b * 64 + p * 16 + c_s) * TDIM + gt) * VDIM;
      float f[25];
#pragma unroll
      for (int j = 0; j < 6; ++j) {
        float4 q4 = *(const float4*)(rp + j * 4);
        f[j * 4 + 0] = q4.x; f[j * 4 + 1] = q4.y;
        f[j * 4 + 2] = q4.z; f[j * 4 + 3] = q4.w;
      }
      f[24] = rp[24];
#pragma unroll
      for (int j = 0; j < 12; ++j) hv[j] = f2bf(f[2 * j]) | (f2bf(f[2 * j + 1]) << 16);
      hv[12] = f2bf(f[24]);
      hv[13] = 0; hv[14] = 0; hv[15] = 0;
    } else {
#pragma unroll
      for (int j = 0; j < 16; ++j) hv[j] = 0;
    }
    int rowb = (c_s * 16 + r) * 16;
#pragma unroll
    for (int bb = 0; bb < 4; ++bb) {
      uint4 wv; wv.x = hv[bb * 4]; wv.y = hv[bb * 4 + 1];
      wv.z = hv[bb * 4 + 2]; wv.w = hv[bb * 4 + 3];
      *(uint4*)&xw_u[rowb + ((bb ^ key) << 2)] = wv;
    }
  };

  const short* bs = wl + lane * 8;

  f4v yacc[4][4];
#pragma unroll
  for (int i = 0; i < 4; ++i)
#pragma unroll
    for (int j = 0; j < 4; ++j) yacc[i][j] = (f4v){0.f, 0.f, 0.f, 0.f};
  float lossA[3] = {0.f, 0.f, 0.f};

  stage_xw(0);
  stage_wl(0);
  __syncthreads();   // initial: wl DMA + xw stores drained

  for (int p = 0; p < 4; ++p) {
#pragma unroll
    for (int s = 0; s < 3; ++s) {
      // y A-frags: issue now, consumed after BB
      const unsigned short* a3p = w3p + (size_t)(s * 4 + p) * 1024 + col16 * 16 + g * 4;
      s4v a3_0 = *(const s4v*)(a3p);
      s4v a3_1 = *(const s4v*)(a3p + 256);
      s4v a3_2 = *(const s4v*)(a3p + 512);
      s4v a3_3 = *(const s4v*)(a3p + 768);

      // ---- z MFMA: 18 x 32x32x16, TWO independent accumulator chains ----
      f16v zaA, zaB;
#pragma unroll
      for (int i = 0; i < 16; ++i) { zaA[i] = 0.f; zaB[i] = 0.f; }
      __builtin_amdgcn_s_setprio(1);
#pragma unroll
      for (int k = 0; k < 9; ++k) {
        int tp = t_l + k;
        int key = (tp + c_sl) & 3;
        int rowb = (c_sl * 16 + tp) * 16;
#pragma unroll
        for (int vh = 0; vh < 2; ++vh) {
          int bb = vh * 2 + half;
          uint4 ua = *(const uint4*)&xw_u[rowb + ((bb ^ key) << 2)];
          s8v a = __builtin_bit_cast(s8v, ua);
          s8v bv = *(const s8v*)(bs + (k * 2 + vh) * 512);
          if (k < 5) zaA = __builtin_amdgcn_mfma_f32_32x32x16_bf16(a, bv, zaA, 0, 0, 0);
          else       zaB = __builtin_amdgcn_mfma_f32_32x32x16_bf16(a, bv, zaB, 0, 0, 0);
        }
      }
      __builtin_amdgcn_s_setprio(0);

      BARRIER_RAW();   // BZ: all waves' wl reads complete

      // issue next wl DMA — lands during loss+BB+y
      if (!(p == 3 && s == 2)) stage_wl(s < 2 ? s + 1 : 0);

      // ---- loss + zly (paired c writes), 2 independent loss chains ----
      const short* xw_s = (const short*)xw_u;
      unsigned* zly_u32 = (unsigned*)zly;
      float lp0 = 0.f, lp1 = 0.f;
#pragma unroll
      for (int q4 = 0; q4 < 8; ++q4) {
        int q = (q4 & 3) | ((q4 & 4) << 1);     // reg pairs (q, q+4)
        int cl = w4 + ((q4 & 4) >> 1);          // c pair base: w4 or w4+2
        int t_rel = (q4 & 3) + 4 * half;
        float z0 = zaA[q] + zaB[q];
        float z1 = zaA[q + 4] + zaB[q + 4];
        int n = t_rel * 32 + col32;
        zly_u32[n * 9 + (cl >> 1)] = f2bf(z0) | (f2bf(z1) << 16);
        if (col32 < VDIM) {
          int tp = t_rel + 8;
          int bb = col32 >> 3;
          int i0 = (cl * 16 + tp) * 32 + ((bb ^ ((tp + cl) & 3)) << 3) + (col32 & 7);
          int i1 = ((cl + 1) * 16 + tp) * 32 + ((bb ^ ((tp + cl + 1) & 3)) << 3) + (col32 & 7);
          float d0 = z0 - bf2f((unsigned short)xw_s[i0]);
          float d1 = z1 - bf2f((unsigned short)xw_s[i1]);
          lp0 = fmaf(d0, d0, lp0);
          lp1 = fmaf(d1, d1, lp1);
        }
      }
      lossA[s] += lp0 + lp1;

      BARRIER_LDS();   // BB: zly visible; wl DMA stays in flight

      // ---- y MFMA: 16 x 16x16x16 per wave, K=16 c ----
      const unsigned* zly_u = (const unsigned*)zly;
      __builtin_amdgcn_s_setprio(1);
#pragma unroll
      for (int u = 0; u < 4; ++u) {
        int n = (wid * 4 + u) * 16 + col16;
        int zo = n * 9 + g * 2;
        uint2 uz; uz.x = zly_u[zo]; uz.y = zly_u[zo + 1];
        s4v bz = __builtin_bit_cast(s4v, uz);
        yacc[0][u] = __builtin_amdgcn_mfma_f32_16x16x16bf16_1k(a3_0, bz, yacc[0][u], 0, 0, 0);
        yacc[1][u] = __builtin_amdgcn_mfma_f32_16x16x16bf16_1k(a3_1, bz, yacc[1][u], 0, 0, 0);
        yacc[2][u] = __builtin_amdgcn_mfma_f32_16x16x16bf16_1k(a3_2, bz, yacc[2][u], 0, 0, 0);
        yacc[3][u] = __builtin_amdgcn_mfma_f32_16x16x16bf16_1k(a3_3, bz, yacc[3][u], 0, 0, 0);
      }
      __builtin_amdgcn_s_setprio(0);

      // stage next c-panel (xw reads done at BB; zly untouched)
      if (s == 2 && p < 3) stage_xw(p + 1);

      __syncthreads();   // full drain: wl DMA landed, xw ds_writes visible, zly reads done
    }
  }

  // ---- loss reduce (xw region as scratch) ----
  {
    float* redf = (float*)xw_u;
#pragma unroll
    for (int s = 0; s < 3; ++s) {
      redf[tid] = lossA[s];
      __syncthreads();
      for (int st = 128; st > 0; st >>= 1) {
        if (tid < st) redf[tid] += redf[tid + st];
        __syncthreads();
      }
      if (tid == 0) lossP[(b * 32 + id) * 3 + s] = redf[0];
      __syncthreads();
    }
  }

  // ---- epilogue: coalesced y = relu(acc*inv + off + x) via LDS stage ----
  {
    float* ystage = (float*)xw_u;   // 4096 f32 = [o16][t8][i32]
#pragma unroll
    for (int mt = 0; mt < 4; ++mt) {
      __syncthreads();   // previous chunk consumed / redf done
#pragma unroll
      for (int u = 0; u < 4; ++u) {
        int n = (wid * 4 + u) * 16 + col16;
        int t_o = n >> 5, i = n & 31;
#pragma unroll
        for (int q = 0; q < 4; ++q)
          ystage[((g * 4 + q) * 8 + t_o) * 32 + i] = yacc[mt][u][q];
      }
      __syncthreads();
      for (int j = tid; j < 3200; j += 256) {
        int ol = j / 200, rem = j - ol * 200;
        int t_o = rem / 25, i = rem - t_o * 25;
        int o = mt * 16 + ol;
        size_t idx = ((size_t)(b * 64 + o) * TDIM + t0 + t_o) * VDIM + i;
        float v = ystage[(ol * 8 + t_o) * 32 + i] * bnf[o] + bnf[64 + o] + x[idx];
        out[idx] = fmaxf(v, 0.f);
      }
    }
  }
}

// ---------------- Kernel 4: finalize loss ----------------
__global__ __launch_bounds__(256) void kfin(const float* __restrict__ lossP,
                                            float* __restrict__ out_loss) {
  __shared__ float red[256];
  int tid = threadIdx.x;
  for (int s = 0; s < 3; ++s) {
    float a = 0.f;
    for (int i = tid; i < 1024; i += 256) a += lossP[i * 3 + s];
    red[tid] = a;
    __syncthreads();
    for (int st = 128; st > 0; st >>= 1) {
      if (tid < st) red[tid] += red[tid + st];
      __syncthreads();
    }
    if (tid == 0) out_loss[s] = red[0] * (1.f / 13107200.f);
    __syncthreads();
  }
}

extern "C" void kernel_launch(void* const* d_in, const int* in_sizes, int n_in,
                              void* d_out, int out_size, void* d_ws, size_t ws_size,
                              hipStream_t stream) {
  (void)in_sizes; (void)n_in; (void)out_size; (void)ws_size;
  const float* x     = (const float*)d_in[0];
  const float* A     = (const float*)d_in[1];
  const float* alpha = (const float*)d_in[2];
  const float* W1    = (const float*)d_in[3];
  const float* b1    = (const float*)d_in[4];
  const float* W2    = (const float*)d_in[5];
  const float* b2    = (const float*)d_in[6];
  const float* W3    = (const float*)d_in[7];
  const float* b3    = (const float*)d_in[8];
  const float* bng   = (const float*)d_in[9];
  const float* bnb   = (const float*)d_in[10];
  const float* bnm   = (const float*)d_in[11];
  const float* bnv   = (const float*)d_in[12];
  float* out = (float*)d_out;
  float* ws  = (float*)d_ws;
  float* out_loss  = out + 13107200;
  float* out_ridge = out + 13107203;
  float* lossP = ws + LOSSP_OFF;

  kmean<<<2048, 256, 0, stream>>>(x, ws);
  kadj<<<96, 256, 0, stream>>>(A, alpha, W1, b1, W2, b2, W3, ws, out_ridge);
  kmain<<<dim3(32, 32), 256, 0, stream>>>(x, b3, bng, bnb, bnm, bnv, ws, out, lossP);
  kfin<<<1, 256, 0, stream>>>(lossP, out_loss);
}

// Round 13
// 111.626 us; speedup vs baseline: 1.9419x; 1.9419x over previous
//
#include <hip/hip_runtime.h>
#include <hip/hip_bf16.h>

#define TDIM 256
#define VDIM 25
#define CDIM 64
#define BDIM 32
#define EPSV 1e-5f

// ws layout
#define XM_OFF     0            // 51200 floats
#define LOSSP_OFF  51200        // 3072 floats (1024 blocks * 3)
#define WPACK_BYTE 229376       // 96 packs * 9216 shorts (bf16 z B-frags, 32x32x16)
#define WL_SH      9216         // shorts per (b,s): 18 kk * (2 hf * 32 n * 8 j)
#define W3P_BYTE   (WPACK_BYTE + 96 * WL_SH * 2)  // 3s*4096 shorts (y A-frags, 16x16x16)

typedef short s4v __attribute__((ext_vector_type(4)));
typedef short s8v __attribute__((ext_vector_type(8)));
typedef float f4v __attribute__((ext_vector_type(4)));
typedef float f16v __attribute__((ext_vector_type(16)));

__device__ __forceinline__ unsigned f2bf(float f) {
  __hip_bfloat16 h = __float2bfloat16(f);
  return (unsigned)__builtin_bit_cast(unsigned short, h);
}
__device__ __forceinline__ float bf2f(unsigned short u) {
  unsigned v = ((unsigned)u) << 16;
  return __builtin_bit_cast(float, v);
}

// ---------------- Kernel 1: xm[b,c,v] = mean over T ----------------
__global__ __launch_bounds__(256) void kmean(const float* __restrict__ x,
                                             float* __restrict__ ws) {
  int bc = blockIdx.x;
  int tid = threadIdx.x;
  int vl = tid & 31, tr = tid >> 5;
  float acc = 0.f;
  if (vl < VDIM) {
    const float* p = x + (size_t)bc * TDIM * VDIM + vl;
    for (int t = tr; t < TDIM; t += 8) acc += p[(size_t)t * VDIM];
  }
  __shared__ float red[256];
  red[tid] = acc;
  __syncthreads();
  if (tr == 0 && vl < VDIM) {
    float s = 0.f;
    for (int r = 0; r < 8; ++r) s += red[r * 32 + vl];
    ws[XM_OFF + bc * VDIM + vl] = s * (1.f / 256.f);
  }
}

// ---------------- Kernel 2: dynamic weights -> packed bf16 fragments ----------------
__global__ __launch_bounds__(256) void kadj(const float* __restrict__ A,
                                            const float* __restrict__ alpha,
                                            const float* __restrict__ W1,
                                            const float* __restrict__ b1,
                                            const float* __restrict__ W2,
                                            const float* __restrict__ b2,
                                            const float* __restrict__ W3,
                                            float* __restrict__ ws,
                                            float* __restrict__ out_ridge) {
  int s = blockIdx.x >> 5, b = blockIdx.x & 31;
  int tid = threadIdx.x;
  __shared__ float xm[CDIM * VDIM];
  __shared__ float w1l[9 * CDIM], w2l[9 * CDIM];
  __shared__ float b1l[9], b2l[9];
  __shared__ float x1l[9 * VDIM], x2l[9 * VDIM];
  __shared__ float red[256];
  __shared__ float wsm[9 * VDIM * VDIM];   // w[k][v][i] f32

  for (int i = tid; i < CDIM * VDIM; i += 256) xm[i] = ws[XM_OFF + b * CDIM * VDIM + i];
  for (int i = tid; i < 9 * CDIM; i += 256) {
    w1l[i] = W1[s * 9 * CDIM + i];
    w2l[i] = W2[s * 9 * CDIM + i];
  }
  if (tid < 9) { b1l[tid] = b1[s * 9 + tid]; b2l[tid] = b2[s * 9 + tid]; }
  __syncthreads();

  if (tid < 9 * VDIM) {
    int ts = tid / VDIM, v = tid % VDIM;
    float a1 = 0.f, a2 = 0.f;
    for (int c = 0; c < CDIM; ++c) {
      float xv = xm[c * VDIM + v];
      a1 = fmaf(xv, w1l[ts * CDIM + c], a1);
      a2 = fmaf(xv, w2l[ts * CDIM + c], a2);
    }
    x1l[tid] = a1 + b1l[ts];
    x2l[tid] = a2 + b2l[ts];
  }
  __syncthreads();

  float al = alpha[0];
  float rid = 0.f;
  for (int idx = tid; idx < 9 * VDIM * VDIM; idx += 256) {
    int k = idx / (VDIM * VDIM);
    int r = (idx / VDIM) % VDIM;   // v
    int q = idx % VDIM;            // i
    float adj = tanhf(x1l[k * VDIM + r] - x2l[k * VDIM + q]);
    rid += adj * adj;
    wsm[idx] = fmaf(adj, al, A[(s * VDIM + r) * VDIM + q]);
  }
  red[tid] = rid;
  __syncthreads();   // wsm + red complete

  // pack z B-frags for 32x32x16: [kk 18][hf 2][n 32][j 8]
  // lane l reads its 8 shorts at wl + l*8:  l*8+j == hf*256 + n*8 + j  (hf=l>>5, n=l&31)
  {
    unsigned short* wp = (unsigned short*)((char*)ws + WPACK_BYTE) + (size_t)(b * 3 + s) * WL_SH;
    for (int idx = tid; idx < WL_SH; idx += 256) {
      int kk = idx >> 9;           // 0..17
      int rem = idx & 511;
      int hf = rem >> 8;           // 0..1
      int n = (rem >> 3) & 31;     // i
      int j = rem & 7;
      int k = kk >> 1, vh = kk & 1;
      int v = vh * 16 + hf * 8 + j;
      float val = (v < VDIM && n < VDIM) ? wsm[(k * VDIM + v) * VDIM + n] : 0.f;
      wp[idx] = (unsigned short)f2bf(val);
    }
  }

  for (int st = 128; st > 0; st >>= 1) {
    if (tid < st) red[tid] += red[tid + st];
    __syncthreads();
  }
  if (tid == 0) out_ridge[s * BDIM + b] = red[0];

  // pack W3 A-frags (16x16x16): [s][p][mt][col16][g4][j4]
  if (b == 0) {
    unsigned short* w3p = (unsigned short*)((char*)ws + W3P_BYTE) + s * 4096;
    for (int idx = tid; idx < 4096; idx += 256) {
      int pm = idx >> 8;          // p*4+mt
      int p = pm >> 2, mt = pm & 3;
      int e = idx & 255;
      int colv = e >> 4, gg = (e >> 2) & 3, jj = e & 3;
      int o = mt * 16 + colv, c = p * 16 + gg * 4 + jj;
      w3p[idx] = (unsigned short)f2bf(W3[(s * CDIM + o) * CDIM + c]);
    }
  }
}

// ---------------- Kernel 3: software-pipelined fused z/y, t-tile = 8 ----------------
// Region n: [dma wl | a3_n load | y_{n-1} | (boundary: stage_xw+bar) | z_n | loss | zly[n&1]] bar
// wl and zly double-buffered; y lags z by one phase -> y MFMAs fill z's dep-chain stalls.
__global__ __launch_bounds__(256, 2) void kmain(const float* __restrict__ x,
                                                const float* __restrict__ b3,
                                                const float* __restrict__ bng,
                                                const float* __restrict__ bnb,
                                                const float* __restrict__ bnm,
                                                const float* __restrict__ bnv,
                                                const float* __restrict__ ws,
                                                float* __restrict__ out,
                                                float* __restrict__ lossP) {
  const int id   = blockIdx.x;                      // 0..31
  const int tile = ((id & 7) << 2) | (id >> 3);     // XCD-contiguous t-chunks
  const int b    = blockIdx.y;
  const int t0   = tile * 8;
  const int tid  = threadIdx.x;
  const int wid  = tid >> 6;
  const int lane = tid & 63;
  const int w4   = wid * 4;
  // z lane constants (32x32)
  const int col32 = lane & 31;
  const int half  = lane >> 5;
  const int t_l   = lane & 7;
  const int c_sl  = w4 + ((lane & 31) >> 3);
  // y lane constants (16x16)
  const int col16 = lane & 15;
  const int g     = (lane >> 4) & 3;

  __shared__ __align__(16) short wl[2][WL_SH];    // 2 x 18432 B
  __shared__ __align__(16) unsigned xw_u[4096];   // 16384 B
  __shared__ __align__(16) short zly[2][4608];    // 2 x 9216 B
  __shared__ float bnf[128];

  if (tid < 64) {
    float inv = bng[tid] / sqrtf(bnv[tid] + EPSV);
    bnf[tid] = inv;
    bnf[64 + tid] = (b3[tid] + b3[64 + tid] + b3[128 + tid] - bnm[tid]) * inv + bnb[tid];
  }

  const unsigned short* wpack = (const unsigned short*)((const char*)ws + WPACK_BYTE);
  const unsigned short* w3p   = (const unsigned short*)((const char*)ws + W3P_BYTE);

  auto stage_wl = [&](int buf, int s2) {
    const char* src = (const char*)(wpack + (size_t)(b * 3 + s2) * WL_SH);
    char* dst = (char*)&wl[buf][0];
#pragma unroll
    for (int j = 0; j < 5; ++j) {
      int off = j * 4096 + wid * 1024;
      if (off < WL_SH * 2) {
        __builtin_amdgcn_global_load_lds(
            (const __attribute__((address_space(1))) unsigned*)(src + off + lane * 16),
            (__attribute__((address_space(3))) unsigned*)(dst + off + lane * 16),
            16, 0, 0);
      }
    }
  };

  auto stage_xw = [&](int p) {
    int c_s = tid >> 4, r = tid & 15;       // row tp = r
    int gt = t0 - 8 + r;
    int key = (r + c_s) & 3;
    unsigned hv[16];
    if (gt >= 0) {
      const float* rp = x + ((size_t)(b * 64 + p * 16 + c_s) * TDIM + gt) * VDIM;
      float f[25];
#pragma unroll
      for (int j = 0; j < 6; ++j) {
        float4 q4 = *(const float4*)(rp + j * 4);
        f[j * 4 + 0] = q4.x; f[j * 4 + 1] = q4.y;
        f[j * 4 + 2] = q4.z; f[j * 4 + 3] = q4.w;
      }
      f[24] = rp[24];
#pragma unroll
      for (int j = 0; j < 12; ++j) hv[j] = f2bf(f[2 * j]) | (f2bf(f[2 * j + 1]) << 16);
      hv[12] = f2bf(f[24]);
      hv[13] = 0; hv[14] = 0; hv[15] = 0;
    } else {
#pragma unroll
      for (int j = 0; j < 16; ++j) hv[j] = 0;
    }
    int rowb = (c_s * 16 + r) * 16;
#pragma unroll
    for (int bb = 0; bb < 4; ++bb) {
      uint4 wv; wv.x = hv[bb * 4]; wv.y = hv[bb * 4 + 1];
      wv.z = hv[bb * 4 + 2]; wv.w = hv[bb * 4 + 3];
      *(uint4*)&xw_u[rowb + ((bb ^ key) << 2)] = wv;
    }
  };

  f4v yacc[4][4];
#pragma unroll
  for (int i = 0; i < 4; ++i)
#pragma unroll
    for (int j = 0; j < 4; ++j) yacc[i][j] = (f4v){0.f, 0.f, 0.f, 0.f};
  float l0 = 0.f, l1 = 0.f, l2 = 0.f;

  // prologue: panel 0 + wl packs 0,1
  stage_xw(0);
  stage_wl(0, 0);
  stage_wl(1, 1);
  __syncthreads();

  s4v a3c0, a3c1, a3c2, a3c3;   // a3 of previous phase (consumed by lagged y)
  int s_cur = 0, p_cur = 0;

  for (int n = 0; n < 12; ++n) {
    const int buf  = n & 1;
    const int pbuf = buf ^ 1;

    // refill buffer freed by z_{n-1} with pack for phase n+1
    if (n >= 1 && n < 11) {
      int np1 = n + 1;
      stage_wl(pbuf, np1 - (np1 / 3) * 3);
    }

    // a3 for phase n (consumed by y_n in region n+1)
    const unsigned short* a3p = w3p + (size_t)(s_cur * 4 + p_cur) * 1024 + col16 * 16 + g * 4;
    s4v a3n0 = *(const s4v*)(a3p);
    s4v a3n1 = *(const s4v*)(a3p + 256);
    s4v a3n2 = *(const s4v*)(a3p + 512);
    s4v a3n3 = *(const s4v*)(a3p + 768);

    // ---- y_{n-1}: 16 x 16x16x16, reads zly[pbuf] ----
    if (n > 0) {
      const unsigned* zly_u = (const unsigned*)&zly[pbuf][0];
#pragma unroll
      for (int u = 0; u < 4; ++u) {
        int nn = (wid * 4 + u) * 16 + col16;
        int zo = nn * 9 + g * 2;
        uint2 uz; uz.x = zly_u[zo]; uz.y = zly_u[zo + 1];
        s4v bz = __builtin_bit_cast(s4v, uz);
        yacc[0][u] = __builtin_amdgcn_mfma_f32_16x16x16bf16_1k(a3c0, bz, yacc[0][u], 0, 0, 0);
        yacc[1][u] = __builtin_amdgcn_mfma_f32_16x16x16bf16_1k(a3c1, bz, yacc[1][u], 0, 0, 0);
        yacc[2][u] = __builtin_amdgcn_mfma_f32_16x16x16bf16_1k(a3c2, bz, yacc[2][u], 0, 0, 0);
        yacc[3][u] = __builtin_amdgcn_mfma_f32_16x16x16bf16_1k(a3c3, bz, yacc[3][u], 0, 0, 0);
      }
    }

    // panel boundary: stage next xw panel, then barrier before z reads it
    if (n > 0 && s_cur == 0) {
      stage_xw(p_cur);
      __syncthreads();
    }

    // ---- z_n: 18 x mfma_f32_32x32x16_bf16, reads wl[buf] + xw ----
    const short* bs = &wl[buf][0] + lane * 8;
    f16v za;
#pragma unroll
    for (int i = 0; i < 16; ++i) za[i] = 0.f;
#pragma unroll
    for (int k = 0; k < 9; ++k) {
      int tp = t_l + k;
      int key = (tp + c_sl) & 3;
      int rowb = (c_sl * 16 + tp) * 16;
#pragma unroll
      for (int vh = 0; vh < 2; ++vh) {
        int bb = vh * 2 + half;
        uint4 ua = *(const uint4*)&xw_u[rowb + ((bb ^ key) << 2)];
        s8v a = __builtin_bit_cast(s8v, ua);
        s8v bv = *(const s8v*)(bs + (k * 2 + vh) * 512);
        za = __builtin_amdgcn_mfma_f32_32x32x16_bf16(a, bv, za, 0, 0, 0);
      }
    }

    // ---- loss + zly[buf] write ----
    {
      const short* xw_s = (const short*)xw_u;
      unsigned* zly_u32 = (unsigned*)&zly[buf][0];
      float lp = 0.f;
#pragma unroll
      for (int q4 = 0; q4 < 8; ++q4) {
        int q = (q4 & 3) | ((q4 & 4) << 1);     // reg pairs (q, q+4)
        int cl = w4 + ((q4 & 4) >> 1);          // c pair base
        int t_rel = (q4 & 3) + 4 * half;
        float z0 = za[q], z1 = za[q + 4];
        int nn = t_rel * 32 + col32;
        zly_u32[nn * 9 + (cl >> 1)] = f2bf(z0) | (f2bf(z1) << 16);
        if (col32 < VDIM) {
          int tp = t_rel + 8;
          int bb = col32 >> 3;
          int i0 = (cl * 16 + tp) * 32 + ((bb ^ ((tp + cl) & 3)) << 3) + (col32 & 7);
          int i1 = ((cl + 1) * 16 + tp) * 32 + ((bb ^ ((tp + cl + 1) & 3)) << 3) + (col32 & 7);
          float d0 = z0 - bf2f((unsigned short)xw_s[i0]);
          float d1 = z1 - bf2f((unsigned short)xw_s[i1]);
          lp = fmaf(d0, d0, fmaf(d1, d1, lp));
        }
      }
      if (s_cur == 0) l0 += lp; else if (s_cur == 1) l1 += lp; else l2 += lp;
    }

    __syncthreads();   // barrier_n: zly[buf] visible, wl DMA drained, xw reads done

    a3c0 = a3n0; a3c1 = a3n1; a3c2 = a3n2; a3c3 = a3n3;
    if (++s_cur == 3) { s_cur = 0; ++p_cur; }
  }

  // final y (phase 11, zly buf 1)
  {
    const unsigned* zly_u = (const unsigned*)&zly[1][0];
#pragma unroll
    for (int u = 0; u < 4; ++u) {
      int nn = (wid * 4 + u) * 16 + col16;
      int zo = nn * 9 + g * 2;
      uint2 uz; uz.x = zly_u[zo]; uz.y = zly_u[zo + 1];
      s4v bz = __builtin_bit_cast(s4v, uz);
      yacc[0][u] = __builtin_amdgcn_mfma_f32_16x16x16bf16_1k(a3c0, bz, yacc[0][u], 0, 0, 0);
      yacc[1][u] = __builtin_amdgcn_mfma_f32_16x16x16bf16_1k(a3c1, bz, yacc[1][u], 0, 0, 0);
      yacc[2][u] = __builtin_amdgcn_mfma_f32_16x16x16bf16_1k(a3c2, bz, yacc[2][u], 0, 0, 0);
      yacc[3][u] = __builtin_amdgcn_mfma_f32_16x16x16bf16_1k(a3c3, bz, yacc[3][u], 0, 0, 0);
    }
  }
  __syncthreads();

  // ---- loss reduce (xw region as scratch) ----
  {
    float lossA[3] = {l0, l1, l2};
    float* redf = (float*)xw_u;
#pragma unroll
    for (int s = 0; s < 3; ++s) {
      redf[tid] = lossA[s];
      __syncthreads();
      for (int st = 128; st > 0; st >>= 1) {
        if (tid < st) redf[tid] += redf[tid + st];
        __syncthreads();
      }
      if (tid == 0) lossP[(b * 32 + id) * 3 + s] = redf[0];
      __syncthreads();
    }
  }

  // ---- epilogue: y = relu(acc*inv + off + x) ----
#pragma unroll
  for (int u = 0; u < 4; ++u) {
    int n = (wid * 4 + u) * 16 + col16;
    int t_out = n >> 5, i = n & 31;
    if (i < VDIM) {
      int gt = t0 + t_out;
#pragma unroll
      for (int mt = 0; mt < 4; ++mt) {
#pragma unroll
        for (int q = 0; q < 4; ++q) {
          int o = mt * 16 + g * 4 + q;
          size_t idx = ((size_t)(b * 64 + o) * TDIM + gt) * VDIM + i;
          float v = yacc[mt][u][q] * bnf[o] + bnf[64 + o] + x[idx];
          out[idx] = fmaxf(v, 0.f);
        }
      }
    }
  }
}

// ---------------- Kernel 4: finalize loss ----------------
__global__ __launch_bounds__(256) void kfin(const float* __restrict__ lossP,
                                            float* __restrict__ out_loss) {
  __shared__ float red[256];
  int tid = threadIdx.x;
  for (int s = 0; s < 3; ++s) {
    float a = 0.f;
    for (int i = tid; i < 1024; i += 256) a += lossP[i * 3 + s];
    red[tid] = a;
    __syncthreads();
    for (int st = 128; st > 0; st >>= 1) {
      if (tid < st) red[tid] += red[tid + st];
      __syncthreads();
    }
    if (tid == 0) out_loss[s] = red[0] * (1.f / 13107200.f);
    __syncthreads();
  }
}

extern "C" void kernel_launch(void* const* d_in, const int* in_sizes, int n_in,
                              void* d_out, int out_size, void* d_ws, size_t ws_size,
                              hipStream_t stream) {
  (void)in_sizes; (void)n_in; (void)out_size; (void)ws_size;
  const float* x     = (const float*)d_in[0];
  const float* A     = (const float*)d_in[1];
  const float* alpha = (const float*)d_in[2];
  const float* W1    = (const float*)d_in[3];
  const float* b1    = (const float*)d_in[4];
  const float* W2    = (const float*)d_in[5];
  const float* b2    = (const float*)d_in[6];
  const float* W3    = (const float*)d_in[7];
  const float* b3    = (const float*)d_in[8];
  const float* bng   = (const float*)d_in[9];
  const float* bnb   = (const float*)d_in[10];
  const float* bnm   = (const float*)d_in[11];
  const float* bnv   = (const float*)d_in[12];
  float* out = (float*)d_out;
  float* ws  = (float*)d_ws;
  float* out_loss  = out + 13107200;
  float* out_ridge = out + 13107203;
  float* lossP = ws + LOSSP_OFF;

  kmean<<<2048, 256, 0, stream>>>(x, ws);
  kadj<<<96, 256, 0, stream>>>(A, alpha, W1, b1, W2, b2, W3, ws, out_ridge);
  kmain<<<dim3(32, 32), 256, 0, stream>>>(x, b3, bng, bnb, bnm, bnv, ws, out, lossP);
  kfin<<<1, 256, 0, stream>>>(lossP, out_loss);
}